// Round 8
// baseline (308.512 us; speedup 1.0000x reference)
//
#include <hip/hip_runtime.h>
#include <math.h>

// Sobel gradient magnitude: in (176, 512, 512) f32 -> out (176, 510, 510) f32
// mag = sqrt((0.5*gx)^2 + (0.5*gy)^2), VALID 3x3 Sobel.
//
// v4: v3 (non-overlapping loads + shfl halo) + PARITY-ALIGNED FULL STORES.
// v3 used 2x float2 stores/row (8B/lane @ stride 16B = partial-line write
// transactions, 2x store instrs). Out-row byte base alternates 16B-aligned
// (even rows) / 8-misaligned (odd rows, 510*4=2040 == 8 mod 16). Row index is
// wave-uniform, so:
//   even rows: lane t stores cols [4t,4t+4) as one aligned dwordx4.
//   odd rows:  lane t stores cols [4t+2,4t+6) as one aligned dwordx4
//              (own m2,m3 + lane t+1's m0,m1 via __shfl_down). Wave seam
//              (tid63 <- tid64) and row head (cols 0,1 by tid127 <- tid0)
//              patched through a 96-byte LDS exchange + one barrier.
// Loads: 8 independent dwordx4/thread (r5: depth-1 pipeline was MLP-starved);
// halo cols via __shfl_down; lane-63 8B halo loaded directly.
// Plain cached stores (r4: nontemporal caused 1.65x write amplification).
// sqrt via __builtin_amdgcn_sqrtf (~1ulp, tolerance 0.03125).

#define OUT_ROWS 6   // 510 = 85 * 6 exactly
#define IN_ROWS  8

__global__ __launch_bounds__(128) void sobel_mag_kernel(
    const float* __restrict__ in, float* __restrict__ out)
{
    const int tid   = threadIdx.x;      // 0..127
    const int lane  = tid & 63;
    const int strip = blockIdx.x;       // 0..84
    const int bc    = blockIdx.y;       // 0..175
    const int W  = 512;
    const int OW = 510;
    const int ox = tid * 4;             // owned column base: 0..508

    const long long in_base  = (long long)bc * (512LL * 512LL)
                             + (long long)(strip * OUT_ROWS) * W + ox;
    const long long out_row0 = (long long)bc * (510LL * 510LL)
                             + (long long)(strip * OUT_ROWS) * OW;

    // ---- Loads: own 4 cols/row, 8 independent dwordx4 (max MLP). ----
    float e[IN_ROWS][4];
    #pragma unroll
    for (int k = 0; k < IN_ROWS; ++k) {
        const float4 lo = *reinterpret_cast<const float4*>(
            in + in_base + (long long)k * W);
        e[k][0] = lo.x; e[k][1] = lo.y; e[k][2] = lo.z; e[k][3] = lo.w;
    }

    // Halo cols ox+4, ox+5: lane+1's e[k][0..1] via shuffle; last lane of
    // each wave loads 8B directly (tid 127's halo is past col 511 -> zeros,
    // feeds only discarded outputs).
    const bool is_last_lane = (lane == 63);
    const bool halo_valid   = (ox + 4) < W;   // false only for tid 127

    float h[IN_ROWS][2];
    if (is_last_lane && halo_valid) {
        #pragma unroll
        for (int k = 0; k < IN_ROWS; ++k) {
            const float2 v = *reinterpret_cast<const float2*>(
                in + in_base + (long long)k * W + 4);
            h[k][0] = v.x; h[k][1] = v.y;
        }
    } else {
        #pragma unroll
        for (int k = 0; k < IN_ROWS; ++k) { h[k][0] = 0.f; h[k][1] = 0.f; }
    }

    #pragma unroll
    for (int k = 0; k < IN_ROWS; ++k) {
        const float s0 = __shfl_down(e[k][0], 1);
        const float s1 = __shfl_down(e[k][1], 1);
        if (!is_last_lane) { h[k][0] = s0; h[k][1] = s1; }
    }

    // Seam LDS: [0] = tid64's odd-row m0,m1 (for tid 63);
    //           [1] = tid0's  odd-row m0,m1 (head cols, stored by tid 127).
    __shared__ float seam[2][3][2];

    // ---- Compute. Even rows stored inline (aligned dwordx4); odd rows
    //      buffered for the post-barrier aligned store. ----
    float modd[3][4];

    #pragma unroll
    for (int orow = 0; orow < OUT_ROWS; ++orow) {
        float t[6], sd[6];
        #pragma unroll
        for (int c = 0; c < 4; ++c) {
            t[c]  = e[orow][c] + 2.0f * e[orow + 1][c] + e[orow + 2][c];
            sd[c] = e[orow][c] - e[orow + 2][c];
        }
        #pragma unroll
        for (int c = 0; c < 2; ++c) {
            t[4 + c]  = h[orow][c] + 2.0f * h[orow + 1][c] + h[orow + 2][c];
            sd[4 + c] = h[orow][c] - h[orow + 2][c];
        }

        float m[4];
        #pragma unroll
        for (int k = 0; k < 4; ++k) {
            const float gx = t[k] - t[k + 2];
            const float gy = sd[k] + 2.0f * sd[k + 1] + sd[k + 2];
            const float hx = 0.5f * gx;
            const float hy = 0.5f * gy;
            m[k] = __builtin_amdgcn_sqrtf(hx * hx + hy * hy);
        }

        if ((orow & 1) == 0) {
            // Even row: base 16B-aligned at col 4*tid.
            float* op = out + out_row0 + (long long)orow * OW + ox;
            if (tid < 127) {
                *reinterpret_cast<float4*>(op) = make_float4(m[0], m[1], m[2], m[3]);
            } else {
                *reinterpret_cast<float2*>(op) = make_float2(m[0], m[1]); // cols 508,509
            }
        } else {
            const int j = orow >> 1;
            modd[j][0] = m[0]; modd[j][1] = m[1];
            modd[j][2] = m[2]; modd[j][3] = m[3];
        }
    }

    if (tid == 64) {
        #pragma unroll
        for (int j = 0; j < 3; ++j) { seam[0][j][0] = modd[j][0]; seam[0][j][1] = modd[j][1]; }
    }
    if (tid == 0) {
        #pragma unroll
        for (int j = 0; j < 3; ++j) { seam[1][j][0] = modd[j][0]; seam[1][j][1] = modd[j][1]; }
    }
    __syncthreads();

    // ---- Odd rows: segment [4t+2, 4t+6) is 16B-aligned. ----
    #pragma unroll
    for (int j = 0; j < 3; ++j) {
        const int orow = 2 * j + 1;
        float n0 = __shfl_down(modd[j][0], 1);
        float n1 = __shfl_down(modd[j][1], 1);
        if (is_last_lane) { n0 = seam[0][j][0]; n1 = seam[0][j][1]; } // valid for tid 63 (tid 127 unused)

        float* oprow = out + out_row0 + (long long)orow * OW;
        if (tid < 127) {
            *reinterpret_cast<float4*>(oprow + ox + 2) =
                make_float4(modd[j][2], modd[j][3], n0, n1);
        } else {
            // Head cols 0,1 (8B-aligned address).
            *reinterpret_cast<float2*>(oprow) =
                make_float2(seam[1][j][0], seam[1][j][1]);
        }
    }
}

extern "C" void kernel_launch(void* const* d_in, const int* in_sizes, int n_in,
                              void* d_out, int out_size, void* d_ws, size_t ws_size,
                              hipStream_t stream) {
    const float* in = (const float*)d_in[0];
    float* out = (float*)d_out;

    dim3 block(128, 1, 1);
    dim3 grid(85, 176, 1);   // 85 row-strips (510/6) x (B*C=176)
    sobel_mag_kernel<<<grid, block, 0, stream>>>(in, out);
}